// Round 11
// baseline (475.380 us; speedup 1.0000x reference)
//
#include <hip/hip_runtime.h>
#include <stdint.h>

#define B_ 512
#define D_ 512
#define C_ 100000
#define CK_ 300000
#define S_ 30.0f
#define COSM_ 0.8775825618903728f
#define SINM_ 0.4794255386042030f
#define TH_ (-0.8775825618903728f)
#define MM_ 0.2397127693021015f
#define EPS_ 1e-12f

#define BM 128
#define BN 96
#define BK 32
#define BUFU 10240   /* ushorts/buffer: A frag-linear 8*512 + B frag-linear 6*1024 */

typedef float f32x4 __attribute__((ext_vector_type(4)));
typedef short s16x8 __attribute__((ext_vector_type(8)));
typedef unsigned long long u64;
typedef unsigned int u32;

#define GLL16(g, l) __builtin_amdgcn_global_load_lds( \
    (const __attribute__((address_space(1))) void*)(g), \
    (__attribute__((address_space(3))) void*)(l), 16, 0, 0)

__device__ __forceinline__ unsigned short f2bf(float f){
  u32 u = __float_as_uint(f);
  u += 0x7FFFu + ((u >> 16) & 1u);
  return (unsigned short)(u >> 16);
}

// ---------------- normalize x rows -> unit bf16 ----------------
__global__ void k_normx(const float* __restrict__ x, unsigned short* __restrict__ xn){
  int row  = blockIdx.x * 4 + (threadIdx.x >> 6);
  int lane = threadIdx.x & 63;
  const float* xr = x + (size_t)row * D_ + lane * 8;
  float4 v0 = *(const float4*)xr;
  float4 v1 = *(const float4*)(xr + 4);
  float s = v0.x*v0.x + v0.y*v0.y + v0.z*v0.z + v0.w*v0.w
          + v1.x*v1.x + v1.y*v1.y + v1.z*v1.z + v1.w*v1.w;
  #pragma unroll
  for (int off = 1; off < 64; off <<= 1) s += __shfl_xor(s, off);
  float inv = 1.f / fmaxf(sqrtf(s), EPS_);
  s16x8 h;
  h[0] = (short)f2bf(v0.x*inv); h[1] = (short)f2bf(v0.y*inv);
  h[2] = (short)f2bf(v0.z*inv); h[3] = (short)f2bf(v0.w*inv);
  h[4] = (short)f2bf(v1.x*inv); h[5] = (short)f2bf(v1.y*inv);
  h[6] = (short)f2bf(v1.z*inv); h[7] = (short)f2bf(v1.w*inv);
  *(s16x8*)(xn + (size_t)row * D_ + lane * 8) = h;
}

// ---------------- zero the per-row reduction buffers ----------------
__global__ void k_init(float* __restrict__ sumexp, u64* __restrict__ packed,
                       float* __restrict__ phi){
  int i = threadIdx.x;
  sumexp[i] = 0.f;
  packed[i] = 0ull;
  phi[i]    = 0.f;
}

// ======= single-pass fused GEMM: gl_lds both operands, frag-linear LDS, 3 blocks/CU =======
// A LDS [0,4096) ushorts:  frag fa (0..7)  at fa*512 + lane*8   (bf16, row=fa*16+lc15, k=lhi*8)
// B LDS [4096,10240):      frag fb (0..5)  at 4096 + fb*1024 + h*512 + lane*8 (fp32 halves)
__global__ __launch_bounds__(256, 3) void k_gemm(
    const unsigned short* __restrict__ xn, const float* __restrict__ w,
    const int* __restrict__ label,
    float* __restrict__ sumexp_g, u64* __restrict__ packed_g,
    float* __restrict__ phi_g)
{
  __shared__ unsigned short st[2*BUFU];   // 40960 B double-buffered
  __shared__ int slab[BM];
  float* mx = (float*)st;                 // epilogue overlay [128][33] = 16896 B

  // bijective XCD-chunked mapping (12500 blocks = 8*1562 + 4):
  // 4 row-tiles sharing one weight column-tile run consecutively on ONE XCD.
  const int bid = blockIdx.x;
  const int xcd = bid & 7;
  const int i8  = bid >> 3;
  const int seq = (xcd < 4) ? (xcd*1563 + i8) : (6252 + (xcd-4)*1562 + i8);
  const int ct = seq >> 2;                 // column tile 0..3124 (32 classes)
  const int rt = seq & 3;                  // row tile 0..3
  const int rowbase = rt * BM;
  const int lcbase  = ct * 32;

  const int tid  = threadIdx.x;
  const int lane = tid & 63;
  const int wid  = tid >> 6;
  const int wm   = wid >> 1, wn = wid & 1; // 2x2 wave grid, wave tile 64x48
  const int lc15 = lane & 15, lhi = lane >> 4;

  if (tid < BM) slab[tid] = label[rowbase + tid];

  // ---- A staging sources: pass p (0,1): frag fa = p*4+wid; dest = p*2048 + tid*8
  const unsigned short* asrc[2];
  #pragma unroll
  for (int p = 0; p < 2; ++p){
    int fa = p*4 + wid;
    asrc[p] = xn + (size_t)(rowbase + fa*16 + lc15) * D_ + lhi*8;
  }
  // ---- B staging sources: pass p (0..2): sB=p*256+tid; fb=sB>>7; h=(sB>>6)&1;
  //      dest = 4096 + p*2048 + tid*8 (ushorts) — linear, wave-uniform base + lane*16B
  const float* bsrc[3];
  #pragma unroll
  for (int p = 0; p < 3; ++p){
    int sB = p*256 + tid;
    int fb = sB >> 7, h = (sB >> 6) & 1;
    int wn_s = fb / 3, n_s = fb % 3;
    int wrow = ct*BN + (wn_s*16 + lc15)*3 + n_s;   // subcenter n_s of class wn_s*16+lc15
    bsrc[p] = w + (size_t)wrow * D_ + lhi*8 + h*4;
  }

  // ---- fragment read offsets: base + lane*16B (conflict-free by construction)
  int aoff[4];
  #pragma unroll
  for (int m = 0; m < 4; ++m) aoff[m] = (wm*4 + m)*512 + lane*8;          // ushort idx
  int bfoff[3];
  #pragma unroll
  for (int n = 0; n < 3; ++n) bfoff[n] = 2048 + (wn*3 + n)*512 + lane*4;  // float idx

#define STAGE(BUFB, KT) do{                                                 \
    _Pragma("unroll")                                                       \
    for (int p = 0; p < 2; ++p)                                             \
      GLL16(asrc[p] + (KT)*BK, &st[(BUFB) + p*2048 + tid*8]);               \
    _Pragma("unroll")                                                       \
    for (int p = 0; p < 3; ++p)                                             \
      GLL16(bsrc[p] + (size_t)(KT)*BK, &st[(BUFB) + 4096 + p*2048 + tid*8]);\
  }while(0)

  f32x4 acc[4][3] = {};
  float sq[3] = {0.f, 0.f, 0.f};

  // ---- prologue: tile 0 into buffer 0 (5 loads/thread)
  STAGE(0, 0);

  #pragma unroll
  for (int t = 0; t < 16; ++t){
    if (t < 15){
      STAGE(((t+1)&1)*BUFU, t+1);
      asm volatile("s_waitcnt vmcnt(5)" ::: "memory");   // tile t (oldest 5) landed
    } else {
      asm volatile("s_waitcnt vmcnt(0)" ::: "memory");
    }
    __builtin_amdgcn_s_barrier();
    asm volatile("" ::: "memory");
    {
      const unsigned short* ab = &st[(t&1)*BUFU];
      const float* bb = (const float*)ab;
      s16x8 af[4];
      #pragma unroll
      for (int m = 0; m < 4; ++m) af[m] = *(const s16x8*)(ab + aoff[m]);
      s16x8 bfr[3];
      #pragma unroll
      for (int n = 0; n < 3; ++n){
        f32x4 b0 = *(const f32x4*)(bb + bfoff[n]);
        f32x4 b1 = *(const f32x4*)(bb + bfoff[n] + 256);
        sq[n] += b0[0]*b0[0] + b0[1]*b0[1] + b0[2]*b0[2] + b0[3]*b0[3]
               + b1[0]*b1[0] + b1[1]*b1[1] + b1[2]*b1[2] + b1[3]*b1[3];
        union { s16x8 h; u32 u[4]; } pk;
        asm("v_cvt_pk_bf16_f32 %0, %1, %2" : "=v"(pk.u[0]) : "v"(b0[0]), "v"(b0[1]));
        asm("v_cvt_pk_bf16_f32 %0, %1, %2" : "=v"(pk.u[1]) : "v"(b0[2]), "v"(b0[3]));
        asm("v_cvt_pk_bf16_f32 %0, %1, %2" : "=v"(pk.u[2]) : "v"(b1[0]), "v"(b1[1]));
        asm("v_cvt_pk_bf16_f32 %0, %1, %2" : "=v"(pk.u[3]) : "v"(b1[2]), "v"(b1[3]));
        bfr[n] = pk.h;
      }
      #pragma unroll
      for (int m = 0; m < 4; ++m)
        #pragma unroll
        for (int n = 0; n < 3; ++n)
          acc[m][n] = __builtin_amdgcn_mfma_f32_16x16x32_bf16(af[m], bfr[n], acc[m][n], 0, 0, 0);
    }
    asm volatile("" ::: "memory");
    __builtin_amdgcn_s_barrier();
  }
#undef STAGE

  // ---- weight-row inverse norms: fold k-slices across lhi (exact fp32)
  float inv[3];
  #pragma unroll
  for (int n = 0; n < 3; ++n){
    float s = sq[n];
    s += __shfl_xor(s, 16);
    s += __shfl_xor(s, 32);
    inv[n] = 1.f / fmaxf(sqrtf(s), EPS_);
  }

  // ---- subcenter max in-register; phi at label; write mx (overlay, post-barrier)
  {
    int cls = wn*16 + lc15;
    #pragma unroll
    for (int m = 0; m < 4; ++m){
      #pragma unroll
      for (int r = 0; r < 4; ++r){
        int rl = wm*64 + m*16 + lhi*4 + r;
        float v = fmaxf(fmaxf(acc[m][0][r]*inv[0], acc[m][1][r]*inv[1]), acc[m][2][r]*inv[2]);
        if (slab[rl] - lcbase == cls){
          float cy = v;
          float s2 = fminf(fmaxf(1.f - cy*cy, 0.f), 1.f);
          float sy = sqrtf(s2);
          float ph = cy*COSM_ - sy*SINM_;
          if (!(cy - TH_ > 0.f)) ph = cy - MM_;
          phi_g[rowbase + rl] = ph;        // unique writer
          v = ph;
        }
        mx[rl*33 + cls] = v;
      }
    }
  }
  __syncthreads();

  // ---- per-row LSE + argmax over this block's 32 classes: 2 threads per row
  {
    int row  = tid >> 1;
    int half = tid & 1;
    int grow = rowbase + row;
    float se = 0.f;
    u64 pk = 0ull;
    #pragma unroll
    for (int c = 0; c < 16; ++c){
      int lc = half*16 + c;
      float v = mx[row*33 + lc];
      se += __expf(S_*v - S_);
      u32 u = __float_as_uint(v);
      u = (v >= 0.f) ? (u | 0x80000000u) : ~u;            // sortable float
      u64 p = ((u64)u << 32) | (u32)~(u32)(lcbase + lc);  // ~idx: first-occurrence ties
      pk = (p > pk) ? p : pk;
    }
    se += __shfl_xor(se, 1);
    u32 lo = (u32)pk, hi2 = (u32)(pk >> 32);
    u32 plo = __shfl_xor(lo, 1), phi2 = __shfl_xor(hi2, 1);
    u64 po = ((u64)phi2 << 32) | plo;
    pk = (po > pk) ? po : pk;
    if (half == 0){
      atomicAdd(&sumexp_g[grow], se);
      atomicMax(&packed_g[grow], pk);
    }
  }
}

// ---------------- finalize: loss + prec1 ----------------
__global__ void k_final(const float* __restrict__ sumexp, const u64* __restrict__ packed,
                        const float* __restrict__ phi, const int* __restrict__ label,
                        float* __restrict__ out){
  int i = threadIdx.x;
  float lse  = S_ + logf(sumexp[i]);
  float loss = lse - S_ * phi[i];
  u32 pred = ~(u32)(packed[i] & 0xFFFFFFFFull);
  float corr = (pred == (u32)label[i]) ? 1.f : 0.f;
  float a = loss, b = corr;
  #pragma unroll
  for (int off = 1; off < 64; off <<= 1){ a += __shfl_xor(a, off); b += __shfl_xor(b, off); }
  __shared__ float sa[8], sb[8];
  if ((i & 63) == 0){ sa[i >> 6] = a; sb[i >> 6] = b; }
  __syncthreads();
  if (i == 0){
    float ta = 0.f, tb = 0.f;
    #pragma unroll
    for (int j = 0; j < 8; ++j){ ta += sa[j]; tb += sb[j]; }
    out[0] = ta / 512.f;
    out[1] = tb * (100.f / 512.f);
  }
}

extern "C" void kernel_launch(void* const* d_in, const int* in_sizes, int n_in,
                              void* d_out, int out_size, void* d_ws, size_t ws_size,
                              hipStream_t stream){
  const float* x     = (const float*)d_in[0];
  const int*   label = (const int*)d_in[1];
  const float* w     = (const float*)d_in[2];
  float* out = (float*)d_out;
  char* ws = (char*)d_ws;

  unsigned short* xn = (unsigned short*)ws;            // 524288 B
  float* sumexp = (float*)(ws + 524288);               // 2048 B
  u64*   packed = (u64*)(ws + 524288 + 2048);          // 4096 B
  float* phi    = (float*)(ws + 524288 + 2048 + 4096); // 2048 B

  k_init <<<1,    512, 0, stream>>>(sumexp, packed, phi);
  k_normx<<<B_/4, 256, 0, stream>>>(x, xn);
  k_gemm <<<(CK_/BN)*4, 256, 0, stream>>>(xn, w, label, sumexp, packed, phi);
  k_final<<<1,    512, 0, stream>>>(sumexp, packed, phi, label, out);
}